// Round 7
// baseline (357.471 us; speedup 1.0000x reference)
//
#include <hip/hip_runtime.h>
#include <hip/hip_bf16.h>

// Llama4 Vision Attention, MI355X bf16-MFMA pipeline.
// B=16 S=576 E=1408 H=16 D=88 (pad 96). fp32 in/out, bf16 internal compute.
// R7: gemm<3> rope epilogue packs pair outputs into u32 stores (halved store
//     count); attn processes 2 q-tiles per block (halved K/V staging).

typedef unsigned short UST;
typedef __attribute__((ext_vector_type(8))) __bf16 bf16x8;
typedef __attribute__((ext_vector_type(4))) float f32x4;
typedef __attribute__((ext_vector_type(8))) UST us8;
typedef __attribute__((ext_vector_type(4))) UST us4;

typedef __attribute__((address_space(3))) unsigned int lds_u32;
typedef const __attribute__((address_space(1))) unsigned int glob_u32;

static __device__ __forceinline__ float bf2f(UST u){
  unsigned int x = ((unsigned int)u) << 16;
  return __builtin_bit_cast(float, x);
}
static __device__ __forceinline__ UST f2bf(float f){
  unsigned int x = __builtin_bit_cast(unsigned int, f);
  x += 0x7fffu + ((x >> 16) & 1u);   // RN-even; inputs finite
  return (UST)(x >> 16);
}

// ------ RoPE tables, feature-major: cosT/sinT[88][576]; d and d^1 share p=d>>1
__global__ void k_tables(float* __restrict__ cosT, float* __restrict__ sinT){
  int s = blockIdx.x;
  int d = threadIdx.x;
  if (d >= 88) return;
  int p = d >> 1;
  int tt = p % 22;
  double comp = (p < 22) ? (double)(s % 24 + 1) : (double)(s / 24 + 1);
  double a = comp * pow(10000.0, -(double)tt / 22.0);
  cosT[d*576 + s] = (float)cos(a);
  sinT[d*576 + s] = (float)sin(a);
}

// ------ zero pads: qa/ka cols 88..95 per row; vt rows d=88..95 --------------
__global__ void k_zero(UST* __restrict__ qa, UST* __restrict__ ka, UST* __restrict__ vt){
  int c = blockIdx.x*256 + threadIdx.x;        // 0..147455 = 256bh * 576
  int bh = c / 576, s = c - bh*576;
  us8 z = {0,0,0,0,0,0,0,0};
  *(us8*)(qa + ((size_t)bh*576 + s)*96 + 88) = z;
  *(us8*)(ka + ((size_t)bh*576 + s)*96 + 88) = z;
  *(us8*)(vt + (size_t)bh*55296 + 50688 + s*8) = z;   // rows 88..95 of [96][576]
}

// ---------------- fp32 -> bf16 cast (vectorized) ----------------------------
__global__ void k_cvt(const float* __restrict__ in, UST* __restrict__ out, int n4){
  int i = blockIdx.x * 256 + threadIdx.x;
  if (i >= n4) return;
  float4 v = ((const float4*)in)[i];
  us4 o; o[0]=f2bf(v.x); o[1]=f2bf(v.y); o[2]=f2bf(v.z); o[3]=f2bf(v.w);
  *(us4*)(out + 4*(size_t)i) = o;
}

// ---------------- fp32 [K][N] -> bf16 [N][K] transpose-convert --------------
__global__ void k_cvt_t(const float* __restrict__ W, UST* __restrict__ Bt, int K, int N){
  __shared__ __align__(16) UST tl[64][70];  // odd dword stride -> low conflict
  int kt = blockIdx.x, nt = blockIdx.y;
  int t = threadIdx.x;
  int k = t >> 2, u = t & 3;
  const float* src = W + (size_t)(kt*64 + k)*N + nt*64 + u*16;
#pragma unroll
  for (int i = 0; i < 4; ++i){
    float4 v = *(const float4*)(src + 4*i);
    UST* d = &tl[k][u*16 + 4*i];
    d[0]=f2bf(v.x); d[1]=f2bf(v.y); d[2]=f2bf(v.z); d[3]=f2bf(v.w);
  }
  __syncthreads();
  int n = t >> 2;
  UST* dst = Bt + (size_t)(nt*64 + n)*K + kt*64 + u*16;
#pragma unroll
  for (int i = 0; i < 2; ++i){
    us8 o;
#pragma unroll
    for (int j = 0; j < 8; ++j) o[j] = tl[u*16 + 8*i + j][n];
    *(us8*)(dst + 8*i) = o;
  }
}

// ---------------- bf16 GEMM (round-2 proven body) + fused epilogues ---------
// EPI 0: fp32 out, stride N (final projection).
// EPI 3: QKV fused — region j = bn/11 uniform per block (1408 = 11*128):
//   j=0/1 (q/k): bias + rope in-register; pair partner = lane^1 via shfl;
//     even lanes store rows 0-1, odd lanes rows 2-3, one u32 (2 bf16) each.
//   j=2   (v):   bias + transpose-store bf16 -> vt [bh][96][576].
template<int EPI>
__global__ __launch_bounds__(256, 2) void k_gemm(
    const UST* __restrict__ A, const UST* __restrict__ Bt,
    const float* __restrict__ bias, void* __restrict__ Cout,
    int M, int N, int K,
    UST* __restrict__ qa, UST* __restrict__ ka, UST* __restrict__ vt,
    const float* __restrict__ cosT, const float* __restrict__ sinT)
{
  __shared__ __align__(16) UST lA[2][128][64];
  __shared__ __align__(16) UST lB[2][128][64];
  const int t = threadIdx.x;
  const int bm = blockIdx.x, bn = blockIdx.y;
  const int wave = t >> 6, lane = t & 63;
  const int lm = lane & 15, g = lane >> 4;
  const int wr = (wave >> 1) << 6, wc = (wave & 1) << 6;
  const int lrow = lane >> 3;                       // 0..7 within 8-row chunk
  const int lcol = (((lane & 7) ^ lrow) << 3);      // pre-swizzled source col
  const UST* Ag = A  + (size_t)(bm*128 + wave*32 + lrow)*K + lcol;
  const UST* Bg = Bt + (size_t)(bn*128 + wave*32 + lrow)*K + lcol;

  f32x4 zero = {0.f,0.f,0.f,0.f};
  f32x4 acc[4][4];
#pragma unroll
  for (int i=0;i<4;++i)
#pragma unroll
    for (int j=0;j<4;++j) acc[i][j] = zero;

  const int nkt = K >> 6;
  auto stage = [&](int kt, int buf){
#pragma unroll
    for (int c = 0; c < 4; ++c){
      __builtin_amdgcn_global_load_lds((glob_u32*)(Ag + (size_t)kt*64 + (size_t)(8*c)*K),
                                       (lds_u32*)(&lA[buf][wave*32 + 8*c][0]), 16, 0, 0);
      __builtin_amdgcn_global_load_lds((glob_u32*)(Bg + (size_t)kt*64 + (size_t)(8*c)*K),
                                       (lds_u32*)(&lB[buf][wave*32 + 8*c][0]), 16, 0, 0);
    }
  };

  stage(0, 0);
  __syncthreads();
  const int swz = (lm & 7) << 3;

  for (int kt = 0; kt < nkt; ++kt){
    const int cur = kt & 1;
    if (kt + 1 < nkt) stage(kt + 1, cur ^ 1);
#pragma unroll
    for (int ks = 0; ks < 2; ++ks){
      bf16x8 af[4], bfv[4];
      const int cb = (ks*32 + g*8) ^ swz;
#pragma unroll
      for (int mf = 0; mf < 4; ++mf)
        af[mf] = __builtin_bit_cast(bf16x8, *(const us8*)&lA[cur][wr + mf*16 + lm][cb]);
#pragma unroll
      for (int nf = 0; nf < 4; ++nf)
        bfv[nf] = __builtin_bit_cast(bf16x8, *(const us8*)&lB[cur][wc + nf*16 + lm][cb]);
#pragma unroll
      for (int mf = 0; mf < 4; ++mf)
#pragma unroll
        for (int nf = 0; nf < 4; ++nf)
          acc[mf][nf] = __builtin_amdgcn_mfma_f32_16x16x32_bf16(af[mf], bfv[nf], acc[mf][nf], 0, 0, 0);
    }
    __syncthreads();   // drains vmcnt -> next buffer ready; protects buffer reuse
  }

  if (EPI == 0){
#pragma unroll
    for (int nf = 0; nf < 4; ++nf){
      const int col = bn*128 + wc + nf*16 + lm;
      const float bv = bias[col];
#pragma unroll
      for (int mf = 0; mf < 4; ++mf){
        const size_t rb = (size_t)(bm*128 + wr + mf*16 + g*4);
#pragma unroll
        for (int r = 0; r < 4; ++r)
          ((float*)Cout)[(rb + r)*(size_t)N + col] = acc[mf][nf][r] + bv;
      }
    }
  } else {
    const int j = bn / 11;               // 0 q, 1 k, 2 v (uniform per block)
    const int bnr = bn - j*11;
    if (j == 2){
#pragma unroll
      for (int nf = 0; nf < 4; ++nf){
        const int cv = bnr*128 + wc + nf*16 + lm;   // v-feature 0..1407
        const float bv = bias[2816 + cv];
        const int h = cv / 88, d = cv - h*88;
#pragma unroll
        for (int mf = 0; mf < 4; ++mf){
          const int rb = bm*128 + wr + mf*16 + g*4; // global row (b*576+s)
          const int b2 = rb / 576, s = rb - b2*576; // 4-row span never crosses b
          UST* dst = vt + ((size_t)((b2*16 + h)*96 + d))*576 + s;
          us4 pk;
#pragma unroll
          for (int r = 0; r < 4; ++r) pk[r] = f2bf(acc[mf][nf][r] + bv);
          *(us4*)dst = pk;
        }
      }
    } else {
      UST* outp = j ? ka : qa;
      const float sc = j ? 1.0f : 0.10660035817780521f;   // 88^-0.5 into q
      const bool even = (lm & 1) == 0;
      const int r0 = (lm & 1) * 2;       // even lane stores rows 0-1, odd 2-3
#pragma unroll
      for (int nf = 0; nf < 4; ++nf){
        const int cv = bnr*128 + wc + nf*16 + lm;   // q/k feature 0..1407
        const float bv = bias[j*1408 + cv];
        const int h = cv / 88, d = cv - h*88;
        const int de = d & ~1;                      // pair-base (cosT[d]==cosT[d^1])
        const float* cT = cosT + d*576;
        const float* sT = sinT + d*576;
#pragma unroll
        for (int mf = 0; mf < 4; ++mf){
          const int rb = bm*128 + wr + mf*16 + g*4;
          const int b2 = rb / 576, s = rb - b2*576;
          float2 c2 = *(const float2*)(cT + s + r0);
          float2 s2 = *(const float2*)(sT + s + r0);
          UST* dstE = outp + ((size_t)(b2*16 + h)*576 + s)*96 + de;
          float vs[4], vo[4];
#pragma unroll
          for (int r = 0; r < 4; ++r){
            vs[r] = acc[mf][nf][r] + bv;            // own column, all rows
            vo[r] = __shfl_xor(vs[r], 1, 64);       // partner column
          }
          float cc[2] = {c2.x, c2.y}, ss[2] = {s2.x, s2.y};
#pragma unroll
          for (int rr = 0; rr < 2; ++rr){
            const int r = r0 + rr;
            float x0 = even ? vs[r] : vo[r];        // value at d even
            float x1 = even ? vo[r] : vs[r];        // value at d odd
            float o0 = (x0*cc[rr] - x1*ss[rr])*sc;
            float o1 = (x0*ss[rr] + x1*cc[rr])*sc;
            unsigned int pk = (unsigned int)f2bf(o0) | ((unsigned int)f2bf(o1) << 16);
            *(unsigned int*)(dstE + (size_t)r*96) = pk;
          }
        }
      }
    }
  }
}

// ---------------- flash attention: 2 q-tiles (128 rows) per block -----------
// grid (256 bh, 5): blocks 0-3 full 128 q-rows, block 4 the last 64 (nset=1).
// Per kvt: stage K/V once, both q-sets consume -> staging/barriers per MFMA halved.
__global__ __launch_bounds__(256, 2) void k_attn(
    const UST* __restrict__ qa, const UST* __restrict__ ka,
    const UST* __restrict__ vt, UST* __restrict__ outp)
{
  __shared__ __align__(16) UST lK[64][104];   // K tile [kv][d]
  __shared__ __align__(16) UST lV[96][72];    // V^T tile [d][kv]
  __shared__ __align__(16) UST lP[4][16][72]; // per-wave P [q][kv] (reused per set)
  const int bh = blockIdx.x, qt2 = blockIdx.y;
  const int nset = (qt2 == 4) ? 1 : 2;
  const int t = threadIdx.x, wave = t >> 6, lane = t & 63;
  const int lm = lane & 15, g = lane >> 4;
  const int h = bh & 15, b = bh >> 4;

  bf16x8 qf[2][3];
  f32x4 zero = {0.f,0.f,0.f,0.f};
  f32x4 acc[2][6];
  float mrun[2][4], lrun[2][4];
#pragma unroll
  for (int u = 0; u < 2; ++u){
    if (u < nset){
      const UST* qp = qa + ((size_t)bh*576 + qt2*128 + u*64 + wave*16 + lm)*96 + g*8;
#pragma unroll
      for (int ks = 0; ks < 3; ++ks)
        qf[u][ks] = __builtin_bit_cast(bf16x8, *(const us8*)(qp + ks*32));
    }
#pragma unroll
    for (int i = 0; i < 6; ++i) acc[u][i] = zero;
#pragma unroll
    for (int r = 0; r < 4; ++r){ mrun[u][r] = -1e30f; lrun[u][r] = 0.f; }
  }

  const UST* kbase = ka + (size_t)bh*576*96;
  const UST* vbase = vt + (size_t)bh*96*576;

  for (int kvt = 0; kvt < 9; ++kvt){
    { // stage K [64][96]
      int r = t >> 2, u4 = t & 3;
      const UST* src = kbase + (size_t)(kvt*64 + r)*96 + u4*24;
#pragma unroll
      for (int i = 0; i < 3; ++i)
        *(uint4*)&lK[r][u4*24 + i*8] = *(const uint4*)(src + i*8);
    }
    if (t < 192){ // stage V^T [96][64]
      int d = t >> 1, hf = t & 1;
      const UST* src = vbase + (size_t)d*576 + kvt*64 + hf*32;
#pragma unroll
      for (int i = 0; i < 4; ++i)
        *(uint4*)&lV[d][hf*32 + i*8] = *(const uint4*)(src + i*8);
    }
    __syncthreads();

#pragma unroll
    for (int u = 0; u < 2; ++u){
      if (u >= nset) continue;
      // QK^T -> sc[nf][r]: S[q][kv = nf*16 + lm]
      f32x4 sc[4];
#pragma unroll
      for (int i = 0; i < 4; ++i) sc[i] = zero;
#pragma unroll
      for (int ks = 0; ks < 3; ++ks){
#pragma unroll
        for (int nf = 0; nf < 4; ++nf){
          bf16x8 kf = __builtin_bit_cast(bf16x8, *(const us8*)&lK[nf*16 + lm][ks*32 + g*8]);
          sc[nf] = __builtin_amdgcn_mfma_f32_16x16x32_bf16(qf[u][ks], kf, sc[nf], 0, 0, 0);
        }
      }
      // online softmax (rows 4g+r; reduce over lm lanes + nf frags)
      float mx[4];
#pragma unroll
      for (int r = 0; r < 4; ++r)
        mx[r] = fmaxf(fmaxf(sc[0][r], sc[1][r]), fmaxf(sc[2][r], sc[3][r]));
#pragma unroll
      for (int m = 1; m <= 8; m <<= 1)
#pragma unroll
        for (int r = 0; r < 4; ++r) mx[r] = fmaxf(mx[r], __shfl_xor(mx[r], m, 64));
      float al[4];
#pragma unroll
      for (int r = 0; r < 4; ++r){
        float mnew = fmaxf(mrun[u][r], mx[r]);
        float corr = __expf(mrun[u][r] - mnew);
        mrun[u][r] = mnew;
        lrun[u][r] *= corr;
        float ls = 0.f;
#pragma unroll
        for (int nf = 0; nf < 4; ++nf){
          float p = __expf(sc[nf][r] - mnew);
          sc[nf][r] = p;
          ls += p;
        }
#pragma unroll
        for (int df = 0; df < 6; ++df) acc[u][df][r] *= corr;
        al[r] = ls;
      }
#pragma unroll
      for (int m = 1; m <= 8; m <<= 1)
#pragma unroll
        for (int r = 0; r < 4; ++r) al[r] += __shfl_xor(al[r], m, 64);
#pragma unroll
      for (int r = 0; r < 4; ++r) lrun[u][r] += al[r];

      // P -> LDS (wave-local), read back as A-frags
#pragma unroll
      for (int nf = 0; nf < 4; ++nf)
#pragma unroll
        for (int r = 0; r < 4; ++r)
          lP[wave][4*g + r][nf*16 + lm] = f2bf(sc[nf][r]);

      bf16x8 pa[2];
#pragma unroll
      for (int ks2 = 0; ks2 < 2; ++ks2)
        pa[ks2] = __builtin_bit_cast(bf16x8, *(const us8*)&lP[wave][lm][ks2*32 + g*8]);
#pragma unroll
      for (int ks2 = 0; ks2 < 2; ++ks2)
#pragma unroll
        for (int df = 0; df < 6; ++df){
          bf16x8 vf = __builtin_bit_cast(bf16x8, *(const us8*)&lV[df*16 + lm][ks2*32 + g*8]);
          acc[u][df] = __builtin_amdgcn_mfma_f32_16x16x32_bf16(pa[ks2], vf, acc[u][df], 0, 0, 0);
        }
    }
    __syncthreads();
  }

#pragma unroll
  for (int u = 0; u < 2; ++u){
    if (u >= nset) continue;
    float inv[4];
#pragma unroll
    for (int r = 0; r < 4; ++r) inv[r] = 1.f / lrun[u][r];
    const size_t rowt = (size_t)b*576 + qt2*128 + u*64 + wave*16;
#pragma unroll
    for (int df = 0; df < 6; ++df){
      int d = df*16 + lm;
      if (d < 88){
#pragma unroll
        for (int r = 0; r < 4; ++r)
          outp[(rowt + 4*g + r)*1408 + h*88 + d] = f2bf(acc[u][df][r] * inv[r]);
      }
    }
  }
}

// ---------------- launch ----------------------------------------------------
extern "C" void kernel_launch(void* const* d_in, const int* in_sizes, int n_in,
                              void* d_out, int out_size, void* d_ws, size_t ws_size,
                              hipStream_t stream)
{
  (void)in_sizes; (void)n_in; (void)out_size; (void)ws_size;
  const float* hs   = (const float*)d_in[0];
  const float* wqkv = (const float*)d_in[1];
  const float* bqkv = (const float*)d_in[2];
  const float* wo   = (const float*)d_in[3];
  const float* bo   = (const float*)d_in[4];
  float* out = (float*)d_out;

  char* w = (char*)d_ws;                       // needs ~127.5 MiB
  UST* A_bf   = (UST*)(w);                     // 25,952,256  (hidden bf16; reused as attn out)
  UST* Bt1    = (UST*)(w + 25952256);          // 11,894,784  (w_qkv^T bf16)
  UST* Bt2    = (UST*)(w + 37847040);          //  3,964,928  (w_o^T bf16)
  UST* qa     = (UST*)(w + 41811968);          // 28,311,552
  UST* ka     = (UST*)(w + 70123520);          // 28,311,552
  UST* vt     = (UST*)(w + 98435072);          // 28,311,552
  float* cosT = (float*)(w + 126746624);       //    202,752
  float* sinT = (float*)(w + 126949376);       //    202,752

  k_tables<<<576, 128, 0, stream>>>(cosT, sinT);
  k_zero<<<576, 256, 0, stream>>>(qa, ka, vt);
  k_cvt<<<12672, 256, 0, stream>>>(hs, A_bf, 3244032);
  k_cvt_t<<<dim3(22, 66), 256, 0, stream>>>(wqkv, Bt1, 1408, 4224);
  k_cvt_t<<<dim3(22, 22), 256, 0, stream>>>(wo, Bt2, 1408, 1408);
  k_gemm<3><<<dim3(72, 33), 256, 0, stream>>>(A_bf, Bt1, bqkv, nullptr, 9216, 4224, 1408,
                                              qa, ka, vt, cosT, sinT);
  k_attn<<<dim3(256, 5), 256, 0, stream>>>(qa, ka, vt, A_bf);
  k_gemm<0><<<dim3(72, 11), 256, 0, stream>>>(A_bf, Bt2, bo, out, 9216, 1408, 1408,
                                              nullptr, nullptr, nullptr, nullptr, nullptr);
}